// Round 2
// baseline (291.883 us; speedup 1.0000x reference)
//
#include <hip/hip_runtime.h>

// Forward-fill: out[r,t] = att[r, last index <= t where wet==0], t=0 forced dry.
// wet is int32 (harness converts bool -> int32).
// Single-pass: each block handles a 1024-elem chunk of one row; carry-in is
// found by a backward ballot-search over preceding wet words (expected ~1 iter
// for random data; terminates at forced-dry t=0, so correct for any input).
__global__ __launch_bounds__(256) void ffill_kernel(
    const float* __restrict__ att,
    const int* __restrict__ wet,
    float* __restrict__ out,
    int T, int chunkElems)
{
    const int r    = blockIdx.y;
    const int c    = blockIdx.x;
    const int tid  = threadIdx.x;
    const int lane = tid & 63;
    const int w    = tid >> 6;
    const long long rowBase = (long long)r * T;
    const int base = c * chunkElems;

    __shared__ float s_wave_val[4];
    __shared__ int   s_wave_has[4];
    __shared__ float s_block_carry;

    // ---- main loads (issued early; independent of lookback) ----
    const int e = base + tid * 4;          // element index within row
    const bool valid = (e < T);            // T % 4 == 0, so all-or-nothing per lane
    float4 a = make_float4(0.f, 0.f, 0.f, 0.f);
    int4 wv = make_int4(1, 1, 1, 1);       // "all wet" for invalid lanes
    if (valid) {
        a  = *reinterpret_cast<const float4*>(att + rowBase + e);
        wv = *reinterpret_cast<const int4*>(wet + rowBase + e);
    }

    // ---- wave 0: backward lookback for the block carry ----
    if (tid < 64) {
        float carry = 0.0f;                // unused for c==0 (t=0 is forced dry)
        int hi = base;                     // exclusive upper bound
        while (hi > 0) {
            const int start = (hi >= 64) ? (hi - 64) : 0;
            const int idx   = start + lane;
            bool dry = false;
            if (idx < hi) {
                dry = (wet[rowBase + idx] == 0) || (idx == 0);
            }
            const unsigned long long m = __ballot(dry);
            if (m != 0ull) {
                const int src = 63 - __clzll(m);
                if (lane == 0) carry = att[rowBase + start + src];
                break;
            }
            hi = start;
        }
        if (lane == 0) s_block_carry = carry;
    }

    // ---- per-lane dry flags over 4 elements ----
    bool d0 = (wv.x == 0);
    bool d1 = (wv.y == 0);
    bool d2 = (wv.z == 0);
    bool d3 = (wv.w == 0);
    if (e == 0) d0 = true;                 // forced dry at t=0
    if (!valid) { d0 = d1 = d2 = d3 = false; }

    const bool has = d0 | d1 | d2 | d3;
    // value at the LAST dry position among this lane's 4 elements
    const float lastval = d3 ? a.w : (d2 ? a.z : (d1 ? a.y : a.x));

    // ---- wave summary ----
    const unsigned long long mask = __ballot(has);
    const int src = (mask != 0ull) ? (63 - __clzll(mask)) : 0;
    const float wval = __shfl(lastval, src);
    if (lane == 0) {
        s_wave_has[w] = (mask != 0ull) ? 1 : 0;
        s_wave_val[w] = wval;
    }
    __syncthreads();

    // ---- each lane's carry-in: rightmost dry among [block carry, waves<w, lanes<lane] ----
    float carry_in = s_block_carry;
    #pragma unroll
    for (int ww = 0; ww < 4; ++ww) {
        if (ww < w && s_wave_has[ww]) carry_in = s_wave_val[ww];
    }
    const unsigned long long pm = mask & ((1ull << lane) - 1ull);
    const int psrc = (pm != 0ull) ? (63 - __clzll(pm)) : 0;
    const float pval = __shfl(lastval, psrc);
    if (pm != 0ull) carry_in = pval;

    // ---- sequential fill over the lane's 4 elements, vector store ----
    if (valid) {
        float running = carry_in;
        float4 o;
        running = d0 ? a.x : running;  o.x = running;
        running = d1 ? a.y : running;  o.y = running;
        running = d2 ? a.z : running;  o.z = running;
        running = d3 ? a.w : running;  o.w = running;
        *reinterpret_cast<float4*>(out + rowBase + e) = o;
    }
}

extern "C" void kernel_launch(void* const* d_in, const int* in_sizes, int n_in,
                              void* d_out, int out_size, void* d_ws, size_t ws_size,
                              hipStream_t stream) {
    const float* att = (const float*)d_in[0];
    const int* wet   = (const int*)d_in[1];
    float* out       = (float*)d_out;

    const int B = 64;
    const int T = in_sizes[0] / B;         // 500000
    const int chunkElems = 1024;           // 256 threads * 4 elems
    const int chunks = (T + chunkElems - 1) / chunkElems;

    dim3 grid(chunks, B);
    dim3 block(256);
    ffill_kernel<<<grid, block, 0, stream>>>(att, wet, out, T, chunkElems);
}